// Round 6
// baseline (1203.522 us; speedup 1.0000x reference)
//
#include <hip/hip_runtime.h>
#include <hip/hip_bf16.h>
#include <math.h>

// N=100000, D=128, H=8, HID=256, QK=64, V=64, PSI_HID=256, OUT=128
#define NPTS 100000
#define NPAD 100352           // 448 * 224 = 784 * 128
#define NGRP 448
#define KST 232               // sKT/sVT row stride (~2-way banks)
#define W0ST 132              // sW0 row stride (4-way banks)
#define HIDST 68              // hid row stride (4-way banks)

typedef __bf16 bf16x8 __attribute__((ext_vector_type(8)));
typedef __bf16 bf16x4 __attribute__((ext_vector_type(4)));
typedef float f32x4 __attribute__((ext_vector_type(4)));

#define MFMA16(a,b,c) __builtin_amdgcn_mfma_f32_16x16x32_bf16((a),(b),(c),0,0,0)
#define SW(row) (((row)&7)<<3)

// ---------- prep: coordinates -> bf16, zero-padded to NPAD ----------
__global__ void k_prep_x(const float* __restrict__ coords, __bf16* __restrict__ Xb) {
  const int total = NPAD * 16;
  for (int c = blockIdx.x * 256 + threadIdx.x; c < total; c += gridDim.x * 256) {
    int row = c >> 4;
    int e8 = (c & 15) << 3;
    bf16x8 v = {};
    if (row < NPTS) {
      const float4* p = (const float4*)(coords + (size_t)row * 128 + e8);
      float4 f0 = p[0], f1 = p[1];
      v[0] = (__bf16)f0.x; v[1] = (__bf16)f0.y; v[2] = (__bf16)f0.z; v[3] = (__bf16)f0.w;
      v[4] = (__bf16)f1.x; v[5] = (__bf16)f1.y; v[6] = (__bf16)f1.z; v[7] = (__bf16)f1.w;
    }
    *(bf16x8*)(Xb + (size_t)row * 128 + e8) = v;
  }
}

// ---------- prep: weights cast/transpose ----------
__global__ void k_prep_w(const float* __restrict__ Wq0, const float* __restrict__ Wk0,
                         const float* __restrict__ Wv0, const float* __restrict__ Wq1,
                         const float* __restrict__ Wk1, const float* __restrict__ Wv1,
                         const float* __restrict__ Wp0, const float* __restrict__ Wp1,
                         __bf16* __restrict__ W0t, __bf16* __restrict__ W1t,
                         __bf16* __restrict__ Wp0t, __bf16* __restrict__ Wp1t) {
  for (int i = blockIdx.x * 256 + threadIdx.x; i < 1343488; i += gridDim.x * 256) {
    if (i < 786432) {                      // W0t [24][256 hid][128 d]
      int g = i >> 15, j = i & 32767;
      int mat = g >> 3, h = g & 7, mcol = j >> 7, k = j & 127;
      const float* src = (mat == 0) ? Wq0 : (mat == 1) ? Wk0 : Wv0;
      W0t[i] = (__bf16)src[h * 32768 + k * 256 + mcol];
    } else if (i < 1179648) {              // W1t [24][64 o][256 hid]
      int t = i - 786432;
      int g = t >> 14, j = t & 16383;
      int mat = g >> 3, h = g & 7, ocol = j >> 8, k = j & 255;
      const float* src = (mat == 0) ? Wq1 : (mat == 1) ? Wk1 : Wv1;
      W1t[t] = (__bf16)src[h * 16384 + k * 64 + ocol];
    } else if (i < 1310720) {              // Wp0t [256][512]
      int t = i - 1179648;
      int col = t >> 9, k = t & 511;
      Wp0t[t] = (__bf16)Wp0[k * 256 + col];
    } else {                               // Wp1t [128][256]
      int t = i - 1310720;
      int col = t >> 8, k = t & 255;
      Wp1t[t] = (__bf16)Wp1[k * 128 + col];
    }
  }
}

// ---------- fused QKV MLPs + kv/sumk partials ----------
// 448 blocks x 448 thr (7 waves), 224 rows/block, 2 blocks/CU (75 KB LDS, <=128 VGPR).
// 96 phases = (h, m, quarter of 64 hid cols). W0 quarter in LDS (reg-prefetched,
// single buffer); W1 B-frags straight from L2; hid wave-private LDS.
__global__ __launch_bounds__(448, 4) void k_mlp(
    const __bf16* __restrict__ Xb, const float* __restrict__ mask,
    const __bf16* __restrict__ W0t, const __bf16* __restrict__ W1t,
    const float* __restrict__ bq0, const float* __restrict__ bq1,
    const float* __restrict__ bk0, const float* __restrict__ bk1,
    const float* __restrict__ bv0, const float* __restrict__ bv1,
    __bf16* __restrict__ qk_ws, float* __restrict__ parts)
{
  __shared__ __bf16 sW0[64 * W0ST];      // 16.5 KB: W0 quarter [64 hid][128 d] padded
  __shared__ __bf16 sKT[64 * KST];       // 29 KB: kk^T [kq][n]
  __shared__ __bf16 sVH[7 * 2176];       // 29.75 KB: union {per-wave hid [2][16][68]} / {v^T [64][KST]}

  const int tid = threadIdx.x, w = tid >> 6, lane = tid & 63;
  const int l15 = lane & 15, lg = lane >> 4;
  const int g = blockIdx.x;
  const int base = g * 224 + w * 32;
  __bf16* myHid = sVH + w * 2176;

  // X rows in registers (read once); masks
  bf16x8 ax[2][4];
  #pragma unroll
  for (int jt = 0; jt < 2; ++jt)
    #pragma unroll
    for (int ks = 0; ks < 4; ++ks)
      ax[jt][ks] = *(const bf16x8*)(Xb + (size_t)(base + jt * 16 + l15) * 128 + ks * 32 + lg * 8);
  float mq[2];
  f32x4 mv[2];
  #pragma unroll
  for (int jt = 0; jt < 2; ++jt) {
    int rq = base + jt * 16 + l15;
    mq[jt] = (rq < NPTS) ? mask[rq] : 0.f;
    int rv = base + jt * 16 + lg * 4;
    if (rv + 3 < NPTS) mv[jt] = *(const f32x4*)&mask[rv];
    else {
      #pragma unroll
      for (int r = 0; r < 4; ++r) mv[jt][r] = (rv + r < NPTS) ? mask[rv + r] : 0.f;
    }
  }

  // W0-quarter staging: regs -> (barrier) -> LDS -> (barrier)
  bf16x8 s0[3];
  auto LOAD = [&](int p) {
    int h = p / 12, m = (p / 4) % 3, q = p & 3;
    const __bf16* w0q = W0t + (size_t)(m * 8 + h) * 32768 + q * 8192;
    #pragma unroll
    for (int i = 0; i < 3; ++i) {
      int u = tid + i * 448;
      if (u < 1024) s0[i] = *(const bf16x8*)(w0q + u * 8);
    }
  };
  auto WRITE = [&]() {
    #pragma unroll
    for (int i = 0; i < 3; ++i) {
      int u = tid + i * 448;
      if (u < 1024) {
        int row = u >> 4, c8 = (u & 15) << 3;
        *(bf16x8*)&sW0[row * W0ST + c8] = s0[i];
      }
    }
  };

  LOAD(0);
  WRITE();
  __syncthreads();

  f32x4 acc2[8];
  bf16x8 ones;
  #pragma unroll
  for (int e = 0; e < 8; ++e) ones[e] = (__bf16)1.0f;

  #pragma unroll 1
  for (int p = 0; p < 96; ++p) {
    const int h = p / 12, m = (p / 4) % 3, q = p & 3;
    if (p + 1 < 96) LOAD(p + 1);          // prefetch next quarter into regs
    if (q == 0) {
      #pragma unroll
      for (int i = 0; i < 8; ++i) acc2[i] = f32x4{0.f, 0.f, 0.f, 0.f};
    }
    const float* b0 = (m == 0) ? bq0 : (m == 1) ? bk0 : bv0;
    const __bf16* w1 = W1t + (size_t)(m * 8 + h) * 16384;

    // ---- layer1 quarter: hid cols [q*64, q*64+64), K = 128 (two 32-col halves) ----
    #pragma unroll
    for (int fih = 0; fih < 2; ++fih) {
      f32x4 a1[2][2] = {};
      #pragma unroll
      for (int ks = 0; ks < 4; ++ks) {
        bf16x8 wa[2];
        #pragma unroll
        for (int f2 = 0; f2 < 2; ++f2) {
          int hl = fih * 32 + f2 * 16 + l15;
          wa[f2] = *(const bf16x8*)&sW0[hl * W0ST + ks * 32 + lg * 8];
        }
        #pragma unroll
        for (int f2 = 0; f2 < 2; ++f2)
          #pragma unroll
          for (int jt = 0; jt < 2; ++jt)
            a1[f2][jt] = MFMA16(wa[f2], ax[jt][ks], a1[f2][jt]);
      }
      // bias + relu -> hid (packed bf16x4; layout [2 jt][16 n][HIDST])
      #pragma unroll
      for (int f2 = 0; f2 < 2; ++f2) {
        f32x4 b0v = *(const f32x4*)&b0[h * 256 + q * 64 + fih * 32 + f2 * 16 + lg * 4];
        #pragma unroll
        for (int jt = 0; jt < 2; ++jt) {
          bf16x4 hv;
          #pragma unroll
          for (int r = 0; r < 4; ++r) {
            float v = a1[f2][jt][r] + b0v[r];
            hv[r] = (__bf16)(v > 0.f ? v : 0.f);
          }
          *(bf16x4*)&myHid[jt * 1088 + l15 * HIDST + fih * 32 + f2 * 16 + lg * 4] = hv;
        }
      }
    }
    // ---- layer2 partial: K-chunk [q*64, q*64+64); W1 B/A-frags from L2 ----
    #pragma unroll
    for (int ks2 = 0; ks2 < 2; ++ks2) {
      bf16x8 hb[2], wf[4];
      #pragma unroll
      for (int jt = 0; jt < 2; ++jt)
        hb[jt] = *(const bf16x8*)&myHid[jt * 1088 + l15 * HIDST + ks2 * 32 + lg * 8];
      #pragma unroll
      for (int f = 0; f < 4; ++f)
        wf[f] = *(const bf16x8*)(w1 + (size_t)(f * 16 + l15) * 256 + q * 64 + ks2 * 32 + lg * 8);
      if (m == 0) {
        #pragma unroll
        for (int ft = 0; ft < 4; ++ft)
          #pragma unroll
          for (int jt = 0; jt < 2; ++jt)
            acc2[ft * 2 + jt] = MFMA16(wf[ft], hb[jt], acc2[ft * 2 + jt]);   // swapped
      } else {
        #pragma unroll
        for (int jt = 0; jt < 2; ++jt)
          #pragma unroll
          for (int f = 0; f < 4; ++f)
            acc2[jt * 4 + f] = MFMA16(hb[jt], wf[f], acc2[jt * 4 + f]);      // normal
      }
    }

    if (q == 3) {
      if (m == 0) {
        // phi(q) -> qk_ws, packed row-major (swapped layout: lane = x-row)
        #pragma unroll
        for (int ft = 0; ft < 4; ++ft) {
          f32x4 b1 = *(const f32x4*)&bq1[h * 64 + ft * 16 + lg * 4];
          #pragma unroll
          for (int jt = 0; jt < 2; ++jt) {
            bf16x4 qv;
            f32x4 a = acc2[ft * 2 + jt];
            #pragma unroll
            for (int r = 0; r < 4; ++r) {
              float v = (a[r] + b1[r]) * mq[jt];
              qv[r] = (__bf16)(v > 0.f ? v + 1.f : __expf(v));
            }
            *(bf16x4*)(qk_ws + ((size_t)h * NPAD + base + jt * 16 + l15) * 64 + ft * 16 + lg * 4) = qv;
          }
        }
      } else if (m == 1) {
        // phi(k), pad rows forced to 0 -> sKT [kq][n]
        #pragma unroll
        for (int f = 0; f < 4; ++f) {
          float b1 = bk1[h * 64 + f * 16 + l15];
          #pragma unroll
          for (int jt = 0; jt < 2; ++jt) {
            bf16x4 k4;
            f32x4 a = acc2[jt * 4 + f];
            #pragma unroll
            for (int r = 0; r < 4; ++r) {
              int row = base + jt * 16 + lg * 4 + r;
              float v = (a[r] + b1) * mv[jt][r];
              k4[r] = (__bf16)((row < NPTS) ? (v > 0.f ? v + 1.f : __expf(v)) : 0.f);
            }
            *(bf16x4*)&sKT[(f * 16 + l15) * KST + w * 32 + jt * 16 + lg * 4] = k4;
          }
        }
      } else {
        __syncthreads();                    // all waves' hid reads done
        // v -> sVH as v^T [j][n]  (overwrites hid union region)
        #pragma unroll
        for (int f = 0; f < 4; ++f) {
          float b1 = bv1[h * 64 + f * 16 + l15];
          #pragma unroll
          for (int jt = 0; jt < 2; ++jt) {
            bf16x4 v4;
            f32x4 a = acc2[jt * 4 + f];
            #pragma unroll
            for (int r = 0; r < 4; ++r)
              v4[r] = (__bf16)((a[r] + b1) * mv[jt][r]);
            *(bf16x4*)&sVH[(f * 16 + l15) * KST + w * 32 + jt * 16 + lg * 4] = v4;
          }
        }
        __syncthreads();                    // vT (and kkT) complete
        // kv tiles (16) + sumk tiles (4): 20 tiles round-robin over 7 waves, K=224
        float* dst = parts + ((size_t)g * 8 + h) * 4160;
        for (int t = w; t < 20; t += 7) {
          f32x4 acc = {};
          if (t < 16) {
            int fi = t >> 2, fj = t & 3;
            #pragma unroll
            for (int ks = 0; ks < 7; ++ks) {
              bf16x8 a = *(const bf16x8*)&sKT[(fi * 16 + l15) * KST + ks * 32 + lg * 8];
              bf16x8 b = *(const bf16x8*)&sVH[(fj * 16 + l15) * KST + ks * 32 + lg * 8];
              acc = MFMA16(a, b, acc);
            }
            #pragma unroll
            for (int r = 0; r < 4; ++r)
              dst[(size_t)(fi * 16 + lg * 4 + r) * 64 + fj * 16 + l15] = acc[r];
          } else {
            int fi = t - 16;
            #pragma unroll
            for (int ks = 0; ks < 7; ++ks) {
              bf16x8 a = *(const bf16x8*)&sKT[(fi * 16 + l15) * KST + ks * 32 + lg * 8];
              acc = MFMA16(a, ones, acc);
            }
            if (l15 == 0) {
              #pragma unroll
              for (int r = 0; r < 4; ++r)
                dst[4096 + fi * 16 + lg * 4 + r] = acc[r];
            }
          }
        }
      }
    }
    if (p + 1 < 96) {
      __syncthreads();   // all reads of sW0 (phase p) done
      WRITE();           // prefetched regs -> sW0
      __syncthreads();   // sW0 ready for phase p+1
    }
  }
}

// ---------- reduce parts -> kvTe bf16 [8][j][k], sumk f32 [512] ----------
__global__ void k_kvt(const float* __restrict__ parts, __bf16* __restrict__ kvTe,
                      float* __restrict__ sumk) {
  int i = blockIdx.x * 256 + threadIdx.x;
  if (i < 32768) {
    int h = i >> 12, rem = i & 4095;
    const float* src = parts + (size_t)h * 4160 + rem;
    float s = 0.f;
    for (int g = 0; g < NGRP; ++g) s += src[(size_t)g * 33280];
    int kq = rem >> 6, j = rem & 63;
    kvTe[((size_t)h * 64 + j) * 64 + kq] = (__bf16)s;
  } else if (i < 33280) {
    int t = i - 32768;
    const float* src = parts + (size_t)(t >> 6) * 4160 + 4096 + (t & 63);
    float s = 0.f;
    for (int g = 0; g < NGRP; ++g) s += src[(size_t)g * 33280];
    sumk[t] = s;
  }
}

// ---------- attention normalize + psi MLP ----------
__global__ __launch_bounds__(512, 2) void k_cd(
    const float* __restrict__ mask, const __bf16* __restrict__ qk_ws,
    const __bf16* __restrict__ kvTe, const float* __restrict__ sumk,
    const __bf16* __restrict__ Wp0t, const __bf16* __restrict__ Wp1t,
    const float* __restrict__ bp0, const float* __restrict__ bp1,
    float* __restrict__ out)
{
  __shared__ __bf16 sWp0c[16384];
  __shared__ __bf16 sCat[8192];
  __shared__ __bf16 sH2[32768];
  __shared__ float sSumk[512];

  const int tid = threadIdx.x, w = tid >> 6, lane = tid & 63, l15 = lane & 15, lg = lane >> 4;
  const int rbase = blockIdx.x * 128 + w * 16;
  __bf16* myCat = sCat + w * 1024;
  __bf16* myH2 = sH2 + w * 4096;

  sSumk[tid] = sumk[tid];

  f32x4 acc1[16] = {};
  for (int h = 0; h < 8; ++h) {
    __syncthreads();
    #pragma unroll
    for (int i = 0; i < 4; ++i) {
      int u = tid + i * 512;
      int col = u >> 3, koff = (u & 7) << 3;
      *(bf16x8*)&sWp0c[(col * 64 + koff) ^ SW(col)] =
          *(const bf16x8*)(Wp0t + (size_t)col * 512 + h * 64 + koff);
    }
    __syncthreads();
    bf16x8 axq[2];
    #pragma unroll
    for (int ks = 0; ks < 2; ++ks)
      axq[ks] = *(const bf16x8*)(qk_ws + ((size_t)h * NPAD + rbase + l15) * 64 + ks * 32 + lg * 8);
    f32x4 accn[4] = {};
    #pragma unroll
    for (int ks = 0; ks < 2; ++ks)
      #pragma unroll
      for (int f = 0; f < 4; ++f) {
        bf16x8 bv = *(const bf16x8*)(kvTe + ((size_t)h * 64 + f * 16 + l15) * 64 + ks * 32 + lg * 8);
        accn[f] = MFMA16(axq[ks], bv, accn[f]);
      }
    float p = 0.f;
    #pragma unroll
    for (int ks = 0; ks < 2; ++ks)
      #pragma unroll
      for (int e = 0; e < 8; ++e)
        p += (float)axq[ks][e] * sSumk[h * 64 + ks * 32 + lg * 8 + e];
    p += __shfl_xor(p, 16);
    p += __shfl_xor(p, 32);
    float dinv[4];
    #pragma unroll
    for (int r = 0; r < 4; ++r) {
      float d = __shfl(p, (lane & 48) + ((lane >> 4) << 2) + r);
      d = (d == 0.f) ? 1e-6f : d;
      dinv[r] = 1.f / d;
    }
    #pragma unroll
    for (int f = 0; f < 4; ++f)
      #pragma unroll
      for (int r = 0; r < 4; ++r) {
        int row = lg * 4 + r;
        myCat[(row * 64 + f * 16 + l15) ^ SW(row)] = (__bf16)(accn[f][r] * dinv[r]);
      }
    #pragma unroll
    for (int ks2 = 0; ks2 < 2; ++ks2) {
      bf16x8 aC = *(const bf16x8*)&myCat[(l15 * 64 + ks2 * 32 + lg * 8) ^ SW(l15)];
      #pragma unroll
      for (int f = 0; f < 16; ++f) {
        bf16x8 bw = *(const bf16x8*)&sWp0c[((f * 16 + l15) * 64 + ks2 * 32 + lg * 8) ^ SW(l15)];
        acc1[f] = MFMA16(aC, bw, acc1[f]);
      }
    }
  }
  #pragma unroll
  for (int f = 0; f < 16; ++f) {
    float bias = bp0[f * 16 + l15];
    #pragma unroll
    for (int r = 0; r < 4; ++r) {
      int row = lg * 4 + r;
      float val = acc1[f][r] + bias;
      val = val > 0.f ? val : 0.f;
      myH2[(row * 256 + f * 16 + l15) ^ SW(row)] = (__bf16)val;
    }
  }
  f32x4 acc2[8] = {};
  #pragma unroll
  for (int ks = 0; ks < 8; ++ks) {
    bf16x8 aH = *(const bf16x8*)&myH2[(l15 * 256 + ks * 32 + lg * 8) ^ SW(l15)];
    #pragma unroll
    for (int f = 0; f < 8; ++f) {
      bf16x8 bw = *(const bf16x8*)(Wp1t + (size_t)(f * 16 + l15) * 256 + ks * 32 + lg * 8);
      acc2[f] = MFMA16(aH, bw, acc2[f]);
    }
  }
  float mvr[4];
  #pragma unroll
  for (int r = 0; r < 4; ++r) {
    int grow = rbase + lg * 4 + r;
    mvr[r] = (grow < NPTS) ? mask[grow] : 0.f;
  }
  #pragma unroll
  for (int f = 0; f < 8; ++f) {
    int col = f * 16 + l15;
    float bias = bp1[col];
    #pragma unroll
    for (int r = 0; r < 4; ++r) {
      int grow = rbase + lg * 4 + r;
      if (grow < NPTS) out[(size_t)grow * 128 + col] = (acc2[f][r] + bias) * mvr[r];
    }
  }
}

extern "C" void kernel_launch(void* const* d_in, const int* in_sizes, int n_in,
                              void* d_out, int out_size, void* d_ws, size_t ws_size,
                              hipStream_t stream) {
  const float* coords = (const float*)d_in[0];
  const float* mask   = (const float*)d_in[1];
  const float* Wq0 = (const float*)d_in[2];
  const float* bq0 = (const float*)d_in[3];
  const float* Wq1 = (const float*)d_in[4];
  const float* bq1 = (const float*)d_in[5];
  const float* Wk0 = (const float*)d_in[6];
  const float* bk0 = (const float*)d_in[7];
  const float* Wk1 = (const float*)d_in[8];
  const float* bk1 = (const float*)d_in[9];
  const float* Wv0 = (const float*)d_in[10];
  const float* bv0 = (const float*)d_in[11];
  const float* Wv1 = (const float*)d_in[12];
  const float* bv1 = (const float*)d_in[13];
  const float* Wp0 = (const float*)d_in[14];
  const float* bp0 = (const float*)d_in[15];
  const float* Wp1 = (const float*)d_in[16];
  const float* bp1 = (const float*)d_in[17];
  float* out = (float*)d_out;

  char* p = (char*)d_ws;
  __bf16* qk_ws = (__bf16*)p; p += (size_t)8 * NPAD * 64 * 2;      // 102,760,448
  __bf16* Xb    = (__bf16*)p; p += (size_t)NPAD * 128 * 2;         //  25,690,112
  __bf16* W0t   = (__bf16*)p; p += (size_t)24 * 32768 * 2;         //   1,572,864
  __bf16* W1t   = (__bf16*)p; p += (size_t)24 * 16384 * 2;         //     786,432
  __bf16* Wp0t  = (__bf16*)p; p += (size_t)256 * 512 * 2;          //     262,144
  __bf16* Wp1t  = (__bf16*)p; p += (size_t)128 * 256 * 2;          //      65,536
  float*  parts = (float*)p;  p += (size_t)NGRP * 8 * 4160 * 4;    //  59,617,280
  float*  sumk  = (float*)p;  p += (size_t)512 * 4;                //       2,048
  __bf16* kvTe  = (__bf16*)p; p += (size_t)8 * 64 * 64 * 2;        //      65,536

  k_prep_x<<<2048, 256, 0, stream>>>(coords, Xb);
  k_prep_w<<<1024, 256, 0, stream>>>(Wq0, Wk0, Wv0, Wq1, Wk1, Wv1, Wp0, Wp1,
                                     W0t, W1t, Wp0t, Wp1t);
  k_mlp<<<NGRP, 448, 0, stream>>>(Xb, mask, W0t, W1t, bq0, bq1, bk0, bk1, bv0, bv1,
                                  qk_ws, parts);
  k_kvt<<<130, 256, 0, stream>>>(parts, kvTe, sumk);
  k_cd<<<784, 512, 0, stream>>>(mask, qk_ws, kvTe, sumk, Wp0t, Wp1t, bp0, bp1, out);
}

// Round 7
// 1145.626 us; speedup vs baseline: 1.0505x; 1.0505x over previous
//
#include <hip/hip_runtime.h>
#include <hip/hip_bf16.h>
#include <math.h>

// N=100000, D=128, H=8, HID=256, QK=64, V=64, PSI_HID=256, OUT=128
#define NPTS 100000
#define NPAD 100352           // 784 * 128
#define NGRP 784
#define KST 136               // sKT/vT row stride
#define W0ST 132              // sW0 row stride
#define HIDST 68              // hid row stride

typedef __bf16 bf16x8 __attribute__((ext_vector_type(8)));
typedef __bf16 bf16x4 __attribute__((ext_vector_type(4)));
typedef float f32x4 __attribute__((ext_vector_type(4)));

#define MFMA16(a,b,c) __builtin_amdgcn_mfma_f32_16x16x32_bf16((a),(b),(c),0,0,0)
#define SW(row) (((row)&7)<<3)

// ---------- prep: weights cast/transpose ----------
__global__ void k_prep_w(const float* __restrict__ Wq0, const float* __restrict__ Wk0,
                         const float* __restrict__ Wv0, const float* __restrict__ Wq1,
                         const float* __restrict__ Wk1, const float* __restrict__ Wv1,
                         const float* __restrict__ Wp0, const float* __restrict__ Wp1,
                         __bf16* __restrict__ W0t, __bf16* __restrict__ W1t,
                         __bf16* __restrict__ Wp0t, __bf16* __restrict__ Wp1t) {
  for (int i = blockIdx.x * 256 + threadIdx.x; i < 1343488; i += gridDim.x * 256) {
    if (i < 786432) {                      // W0t [24][256 hid][128 d]
      int g = i >> 15, j = i & 32767;
      int mat = g >> 3, h = g & 7, mcol = j >> 7, k = j & 127;
      const float* src = (mat == 0) ? Wq0 : (mat == 1) ? Wk0 : Wv0;
      W0t[i] = (__bf16)src[h * 32768 + k * 256 + mcol];
    } else if (i < 1179648) {              // W1t [24][64 o][256 hid]
      int t = i - 786432;
      int g = t >> 14, j = t & 16383;
      int mat = g >> 3, h = g & 7, ocol = j >> 8, k = j & 255;
      const float* src = (mat == 0) ? Wq1 : (mat == 1) ? Wk1 : Wv1;
      W1t[t] = (__bf16)src[h * 16384 + k * 64 + ocol];
    } else if (i < 1310720) {              // Wp0t [256][512]
      int t = i - 1179648;
      int col = t >> 9, k = t & 511;
      Wp0t[t] = (__bf16)Wp0[k * 256 + col];
    } else {                               // Wp1t [128][256]
      int t = i - 1310720;
      int col = t >> 8, k = t & 255;
      Wp1t[t] = (__bf16)Wp1[k * 128 + col];
    }
  }
}

// ---------- fused QKV MLPs + kv/sumk partials ----------
// 784 blocks x 256 thr (4 waves), 128 rows/block, 3 blocks/CU (51.7 KB LDS, ~170 reg budget).
// 96 phases = (h, m, quarter of 64 hid cols). W0 quarter in LDS (reg-prefetched);
// W1 B-frags straight from L2; hid wave-private LDS; kv partials -> bf16 parts.
__global__ __launch_bounds__(256, 3) void k_mlp(
    const float* __restrict__ coords, const float* __restrict__ mask,
    const __bf16* __restrict__ W0t, const __bf16* __restrict__ W1t,
    const float* __restrict__ bq0, const float* __restrict__ bq1,
    const float* __restrict__ bk0, const float* __restrict__ bk1,
    const float* __restrict__ bv0, const float* __restrict__ bv1,
    __bf16* __restrict__ qk_ws, __bf16* __restrict__ parts_kv,
    float* __restrict__ parts_sk)
{
  __shared__ __bf16 sW0[64 * W0ST];      // 16.9 KB: W0 quarter [64 hid][128 d] padded
  __shared__ __bf16 sKT[64 * KST];       // 17.4 KB: kk^T [kq][n 0..127]
  __shared__ __bf16 sVH[64 * KST];       // 17.4 KB: union {4 waves hid [2][16][HIDST]} / {v^T [64][KST]}

  const int tid = threadIdx.x, w = tid >> 6, lane = tid & 63;
  const int l15 = lane & 15, lg = lane >> 4;
  const int g = blockIdx.x;
  const int base = g * 128 + w * 32;
  __bf16* myHid = sVH + w * 2176;

  // X rows f32 -> bf16 registers (read once per block); masks
  bf16x8 ax[2][4];
  #pragma unroll
  for (int jt = 0; jt < 2; ++jt) {
    int row = base + jt * 16 + l15;
    #pragma unroll
    for (int ks = 0; ks < 4; ++ks) {
      bf16x8 v = {};
      if (row < NPTS) {
        const float4* p4 = (const float4*)(coords + (size_t)row * 128 + ks * 32 + lg * 8);
        float4 f0 = p4[0], f1 = p4[1];
        v[0] = (__bf16)f0.x; v[1] = (__bf16)f0.y; v[2] = (__bf16)f0.z; v[3] = (__bf16)f0.w;
        v[4] = (__bf16)f1.x; v[5] = (__bf16)f1.y; v[6] = (__bf16)f1.z; v[7] = (__bf16)f1.w;
      }
      ax[jt][ks] = v;
    }
  }
  float mq[2];
  f32x4 mv[2];
  #pragma unroll
  for (int jt = 0; jt < 2; ++jt) {
    int rq = base + jt * 16 + l15;
    mq[jt] = (rq < NPTS) ? mask[rq] : 0.f;
    int rv = base + jt * 16 + lg * 4;
    #pragma unroll
    for (int r = 0; r < 4; ++r) mv[jt][r] = (rv + r < NPTS) ? mask[rv + r] : 0.f;
  }

  // W0-quarter staging: regs -> (barrier) -> LDS -> (barrier)
  bf16x8 s0[4];
  auto LOAD = [&](int p) {
    int h = p / 12, m = (p / 4) % 3, q = p & 3;
    const __bf16* w0q = W0t + (size_t)(m * 8 + h) * 32768 + q * 8192;
    #pragma unroll
    for (int i = 0; i < 4; ++i) {
      int u = tid + i * 256;
      s0[i] = *(const bf16x8*)(w0q + u * 8);
    }
  };
  auto WRITE = [&]() {
    #pragma unroll
    for (int i = 0; i < 4; ++i) {
      int u = tid + i * 256;
      int row = u >> 4, c8 = (u & 15) << 3;
      *(bf16x8*)&sW0[row * W0ST + c8] = s0[i];
    }
  };

  LOAD(0);
  WRITE();
  __syncthreads();

  f32x4 acc2[8];
  bf16x8 ones;
  #pragma unroll
  for (int e = 0; e < 8; ++e) ones[e] = (__bf16)1.0f;

  #pragma unroll 1
  for (int p = 0; p < 96; ++p) {
    const int h = p / 12, m = (p / 4) % 3, q = p & 3;
    if (p + 1 < 96) LOAD(p + 1);          // prefetch next quarter into regs
    if (q == 0) {
      #pragma unroll
      for (int i = 0; i < 8; ++i) acc2[i] = f32x4{0.f, 0.f, 0.f, 0.f};
    }
    const float* b0 = (m == 0) ? bq0 : (m == 1) ? bk0 : bv0;
    const __bf16* w1 = W1t + (size_t)(m * 8 + h) * 16384;

    // ---- layer1 quarter: hid cols [q*64, q*64+64), K = 128 ----
    #pragma unroll
    for (int fih = 0; fih < 2; ++fih) {
      f32x4 a1[2][2] = {};
      #pragma unroll
      for (int ks = 0; ks < 4; ++ks) {
        bf16x8 wa[2];
        #pragma unroll
        for (int f2 = 0; f2 < 2; ++f2) {
          int hl = fih * 32 + f2 * 16 + l15;
          wa[f2] = *(const bf16x8*)&sW0[hl * W0ST + ks * 32 + lg * 8];
        }
        #pragma unroll
        for (int f2 = 0; f2 < 2; ++f2)
          #pragma unroll
          for (int jt = 0; jt < 2; ++jt)
            a1[f2][jt] = MFMA16(wa[f2], ax[jt][ks], a1[f2][jt]);
      }
      // bias + relu -> hid (packed bf16x4; layout [2 jt][16 n][HIDST])
      #pragma unroll
      for (int f2 = 0; f2 < 2; ++f2) {
        f32x4 b0v = *(const f32x4*)&b0[h * 256 + q * 64 + fih * 32 + f2 * 16 + lg * 4];
        #pragma unroll
        for (int jt = 0; jt < 2; ++jt) {
          bf16x4 hv;
          #pragma unroll
          for (int r = 0; r < 4; ++r) {
            float v = a1[f2][jt][r] + b0v[r];
            hv[r] = (__bf16)(v > 0.f ? v : 0.f);
          }
          *(bf16x4*)&myHid[jt * 1088 + l15 * HIDST + fih * 32 + f2 * 16 + lg * 4] = hv;
        }
      }
    }
    // ---- layer2 partial: K-chunk [q*64, q*64+64); W1 frags from L2 ----
    #pragma unroll
    for (int ks2 = 0; ks2 < 2; ++ks2) {
      bf16x8 hb[2], wf[4];
      #pragma unroll
      for (int jt = 0; jt < 2; ++jt)
        hb[jt] = *(const bf16x8*)&myHid[jt * 1088 + l15 * HIDST + ks2 * 32 + lg * 8];
      #pragma unroll
      for (int f = 0; f < 4; ++f)
        wf[f] = *(const bf16x8*)(w1 + (size_t)(f * 16 + l15) * 256 + q * 64 + ks2 * 32 + lg * 8);
      if (m == 0) {
        #pragma unroll
        for (int ft = 0; ft < 4; ++ft)
          #pragma unroll
          for (int jt = 0; jt < 2; ++jt)
            acc2[ft * 2 + jt] = MFMA16(wf[ft], hb[jt], acc2[ft * 2 + jt]);   // swapped
      } else {
        #pragma unroll
        for (int jt = 0; jt < 2; ++jt)
          #pragma unroll
          for (int f = 0; f < 4; ++f)
            acc2[jt * 4 + f] = MFMA16(hb[jt], wf[f], acc2[jt * 4 + f]);      // normal
      }
    }

    if (q == 3) {
      if (m == 0) {
        // phi(q) -> qk_ws, packed row-major (swapped layout: lane = x-row)
        #pragma unroll
        for (int ft = 0; ft < 4; ++ft) {
          f32x4 b1 = *(const f32x4*)&bq1[h * 64 + ft * 16 + lg * 4];
          #pragma unroll
          for (int jt = 0; jt < 2; ++jt) {
            bf16x4 qv;
            f32x4 a = acc2[ft * 2 + jt];
            #pragma unroll
            for (int r = 0; r < 4; ++r) {
              float v = (a[r] + b1[r]) * mq[jt];
              qv[r] = (__bf16)(v > 0.f ? v + 1.f : __expf(v));
            }
            *(bf16x4*)(qk_ws + ((size_t)h * NPAD + base + jt * 16 + l15) * 64 + ft * 16 + lg * 4) = qv;
          }
        }
      } else if (m == 1) {
        // phi(k), pad rows forced to 0 -> sKT [kq][n]
        #pragma unroll
        for (int f = 0; f < 4; ++f) {
          float b1 = bk1[h * 64 + f * 16 + l15];
          #pragma unroll
          for (int jt = 0; jt < 2; ++jt) {
            bf16x4 k4;
            f32x4 a = acc2[jt * 4 + f];
            #pragma unroll
            for (int r = 0; r < 4; ++r) {
              int row = base + jt * 16 + lg * 4 + r;
              float v = (a[r] + b1) * mv[jt][r];
              k4[r] = (__bf16)((row < NPTS) ? (v > 0.f ? v + 1.f : __expf(v)) : 0.f);
            }
            *(bf16x4*)&sKT[(f * 16 + l15) * KST + w * 32 + jt * 16 + lg * 4] = k4;
          }
        }
      } else {
        __syncthreads();                    // all waves' hid reads done
        // v -> sVH as v^T [j][n]  (overwrites hid union region)
        #pragma unroll
        for (int f = 0; f < 4; ++f) {
          float b1 = bv1[h * 64 + f * 16 + l15];
          #pragma unroll
          for (int jt = 0; jt < 2; ++jt) {
            bf16x4 v4;
            f32x4 a = acc2[jt * 4 + f];
            #pragma unroll
            for (int r = 0; r < 4; ++r)
              v4[r] = (__bf16)((a[r] + b1) * mv[jt][r]);
            *(bf16x4*)&sVH[(f * 16 + l15) * KST + w * 32 + jt * 16 + lg * 4] = v4;
          }
        }
        __syncthreads();                    // vT (and kkT) complete
        // kv tiles (16, -> bf16 parts) + sumk tiles (4, -> f32 parts); K = 128
        __bf16* dkv = parts_kv + ((size_t)g * 8 + h) * 4096;
        float* dsk = parts_sk + (size_t)g * 512 + h * 64;
        for (int t = w; t < 20; t += 4) {
          f32x4 acc = {};
          if (t < 16) {
            int fi = t >> 2, fj = t & 3;
            #pragma unroll
            for (int ks = 0; ks < 4; ++ks) {
              bf16x8 a = *(const bf16x8*)&sKT[(fi * 16 + l15) * KST + ks * 32 + lg * 8];
              bf16x8 b = *(const bf16x8*)&sVH[(fj * 16 + l15) * KST + ks * 32 + lg * 8];
              acc = MFMA16(a, b, acc);
            }
            #pragma unroll
            for (int r = 0; r < 4; ++r)
              dkv[(size_t)(fi * 16 + lg * 4 + r) * 64 + fj * 16 + l15] = (__bf16)acc[r];
          } else {
            int fi = t - 16;
            #pragma unroll
            for (int ks = 0; ks < 4; ++ks) {
              bf16x8 a = *(const bf16x8*)&sKT[(fi * 16 + l15) * KST + ks * 32 + lg * 8];
              acc = MFMA16(a, ones, acc);
            }
            if (l15 == 0) {
              #pragma unroll
              for (int r = 0; r < 4; ++r)
                dsk[fi * 16 + lg * 4 + r] = acc[r];
            }
          }
        }
      }
    }
    if (p + 1 < 96) {
      __syncthreads();   // all reads of sW0 (phase p) done
      WRITE();           // prefetched regs -> sW0
      __syncthreads();   // sW0 ready for phase p+1
    }
  }
}

// ---------- reduce parts -> kvTe bf16 [8][j][k], sumk f32 [512] ----------
__global__ void k_kvt(const __bf16* __restrict__ parts_kv, const float* __restrict__ parts_sk,
                      __bf16* __restrict__ kvTe, float* __restrict__ sumk) {
  int i = blockIdx.x * 256 + threadIdx.x;
  if (i < 32768) {
    float s = 0.f;
    for (int g = 0; g < NGRP; ++g) s += (float)parts_kv[(size_t)g * 32768 + i];
    int h = i >> 12, rem = i & 4095;
    int kq = rem >> 6, j = rem & 63;
    kvTe[((size_t)h * 64 + j) * 64 + kq] = (__bf16)s;
  } else if (i < 33280) {
    int t = i - 32768;
    float s = 0.f;
    for (int g = 0; g < NGRP; ++g) s += parts_sk[(size_t)g * 512 + t];
    sumk[t] = s;
  }
}

// ---------- attention normalize + psi MLP ----------
__global__ __launch_bounds__(512, 2) void k_cd(
    const float* __restrict__ mask, const __bf16* __restrict__ qk_ws,
    const __bf16* __restrict__ kvTe, const float* __restrict__ sumk,
    const __bf16* __restrict__ Wp0t, const __bf16* __restrict__ Wp1t,
    const float* __restrict__ bp0, const float* __restrict__ bp1,
    float* __restrict__ out)
{
  __shared__ __bf16 sWp0c[16384];
  __shared__ __bf16 sCat[8192];
  __shared__ __bf16 sH2[32768];
  __shared__ float sSumk[512];

  const int tid = threadIdx.x, w = tid >> 6, lane = tid & 63, l15 = lane & 15, lg = lane >> 4;
  const int rbase = blockIdx.x * 128 + w * 16;
  __bf16* myCat = sCat + w * 1024;
  __bf16* myH2 = sH2 + w * 4096;

  sSumk[tid] = sumk[tid];

  f32x4 acc1[16] = {};
  for (int h = 0; h < 8; ++h) {
    __syncthreads();
    #pragma unroll
    for (int i = 0; i < 4; ++i) {
      int u = tid + i * 512;
      int col = u >> 3, koff = (u & 7) << 3;
      *(bf16x8*)&sWp0c[(col * 64 + koff) ^ SW(col)] =
          *(const bf16x8*)(Wp0t + (size_t)col * 512 + h * 64 + koff);
    }
    __syncthreads();
    bf16x8 axq[2];
    #pragma unroll
    for (int ks = 0; ks < 2; ++ks)
      axq[ks] = *(const bf16x8*)(qk_ws + ((size_t)h * NPAD + rbase + l15) * 64 + ks * 32 + lg * 8);
    f32x4 accn[4] = {};
    #pragma unroll
    for (int ks = 0; ks < 2; ++ks)
      #pragma unroll
      for (int f = 0; f < 4; ++f) {
        bf16x8 bv = *(const bf16x8*)(kvTe + ((size_t)h * 64 + f * 16 + l15) * 64 + ks * 32 + lg * 8);
        accn[f] = MFMA16(axq[ks], bv, accn[f]);
      }
    float p = 0.f;
    #pragma unroll
    for (int ks = 0; ks < 2; ++ks)
      #pragma unroll
      for (int e = 0; e < 8; ++e)
        p += (float)axq[ks][e] * sSumk[h * 64 + ks * 32 + lg * 8 + e];
    p += __shfl_xor(p, 16);
    p += __shfl_xor(p, 32);
    float dinv[4];
    #pragma unroll
    for (int r = 0; r < 4; ++r) {
      float d = __shfl(p, (lane & 48) + ((lane >> 4) << 2) + r);
      d = (d == 0.f) ? 1e-6f : d;
      dinv[r] = 1.f / d;
    }
    #pragma unroll
    for (int f = 0; f < 4; ++f)
      #pragma unroll
      for (int r = 0; r < 4; ++r) {
        int row = lg * 4 + r;
        myCat[(row * 64 + f * 16 + l15) ^ SW(row)] = (__bf16)(accn[f][r] * dinv[r]);
      }
    #pragma unroll
    for (int ks2 = 0; ks2 < 2; ++ks2) {
      bf16x8 aC = *(const bf16x8*)&myCat[(l15 * 64 + ks2 * 32 + lg * 8) ^ SW(l15)];
      #pragma unroll
      for (int f = 0; f < 16; ++f) {
        bf16x8 bw = *(const bf16x8*)&sWp0c[((f * 16 + l15) * 64 + ks2 * 32 + lg * 8) ^ SW(l15)];
        acc1[f] = MFMA16(aC, bw, acc1[f]);
      }
    }
  }
  #pragma unroll
  for (int f = 0; f < 16; ++f) {
    float bias = bp0[f * 16 + l15];
    #pragma unroll
    for (int r = 0; r < 4; ++r) {
      int row = lg * 4 + r;
      float val = acc1[f][r] + bias;
      val = val > 0.f ? val : 0.f;
      myH2[(row * 256 + f * 16 + l15) ^ SW(row)] = (__bf16)val;
    }
  }
  f32x4 acc2[8] = {};
  #pragma unroll
  for (int ks = 0; ks < 8; ++ks) {
    bf16x8 aH = *(const bf16x8*)&myH2[(l15 * 256 + ks * 32 + lg * 8) ^ SW(l15)];
    #pragma unroll
    for (int f = 0; f < 8; ++f) {
      bf16x8 bw = *(const bf16x8*)(Wp1t + (size_t)(f * 16 + l15) * 256 + ks * 32 + lg * 8);
      acc2[f] = MFMA16(aH, bw, acc2[f]);
    }
  }
  float mvr[4];
  #pragma unroll
  for (int r = 0; r < 4; ++r) {
    int grow = rbase + lg * 4 + r;
    mvr[r] = (grow < NPTS) ? mask[grow] : 0.f;
  }
  #pragma unroll
  for (int f = 0; f < 8; ++f) {
    int col = f * 16 + l15;
    float bias = bp1[col];
    #pragma unroll
    for (int r = 0; r < 4; ++r) {
      int grow = rbase + lg * 4 + r;
      if (grow < NPTS) out[(size_t)grow * 128 + col] = (acc2[f][r] + bias) * mvr[r];
    }
  }
}

extern "C" void kernel_launch(void* const* d_in, const int* in_sizes, int n_in,
                              void* d_out, int out_size, void* d_ws, size_t ws_size,
                              hipStream_t stream) {
  const float* coords = (const float*)d_in[0];
  const float* mask   = (const float*)d_in[1];
  const float* Wq0 = (const float*)d_in[2];
  const float* bq0 = (const float*)d_in[3];
  const float* Wq1 = (const float*)d_in[4];
  const float* bq1 = (const float*)d_in[5];
  const float* Wk0 = (const float*)d_in[6];
  const float* bk0 = (const float*)d_in[7];
  const float* Wk1 = (const float*)d_in[8];
  const float* bk1 = (const float*)d_in[9];
  const float* Wv0 = (const float*)d_in[10];
  const float* bv0 = (const float*)d_in[11];
  const float* Wv1 = (const float*)d_in[12];
  const float* bv1 = (const float*)d_in[13];
  const float* Wp0 = (const float*)d_in[14];
  const float* bp0 = (const float*)d_in[15];
  const float* Wp1 = (const float*)d_in[16];
  const float* bp1 = (const float*)d_in[17];
  float* out = (float*)d_out;

  char* p = (char*)d_ws;
  __bf16* qk_ws    = (__bf16*)p; p += (size_t)8 * NPAD * 64 * 2;   // 102,760,448
  __bf16* W0t      = (__bf16*)p; p += (size_t)24 * 32768 * 2;      //   1,572,864
  __bf16* W1t      = (__bf16*)p; p += (size_t)24 * 16384 * 2;      //     786,432
  __bf16* Wp0t     = (__bf16*)p; p += (size_t)256 * 512 * 2;       //     262,144
  __bf16* Wp1t     = (__bf16*)p; p += (size_t)128 * 256 * 2;       //      65,536
  __bf16* parts_kv = (__bf16*)p; p += (size_t)NGRP * 8 * 4096 * 2; //  51,380,224
  float*  parts_sk = (float*)p;  p += (size_t)NGRP * 512 * 4;      //   1,605,632
  float*  sumk     = (float*)p;  p += (size_t)512 * 4;             //       2,048
  __bf16* kvTe     = (__bf16*)p; p += (size_t)8 * 64 * 64 * 2;     //      65,536

  k_prep_w<<<1024, 256, 0, stream>>>(Wq0, Wk0, Wv0, Wq1, Wk1, Wv1, Wp0, Wp1,
                                     W0t, W1t, Wp0t, Wp1t);
  k_mlp<<<NGRP, 256, 0, stream>>>(coords, mask, W0t, W1t, bq0, bq1, bk0, bk1,
                                  bv0, bv1, qk_ws, parts_kv, parts_sk);
  k_kvt<<<130, 256, 0, stream>>>(parts_kv, parts_sk, kvTe, sumk);
  k_cd<<<NGRP, 512, 0, stream>>>(mask, qk_ws, kvTe, sumk, Wp0t, Wp1t, bp0, bp1, out);
}

// Round 9
// 591.719 us; speedup vs baseline: 2.0339x; 1.9361x over previous
//
#include <hip/hip_runtime.h>
#include <hip/hip_bf16.h>
#include <math.h>

// N=100000, D=128, H=8, HID=256, QK=64, V=64, PSI_HID=256, OUT=128
#define NPTS 100000
#define NPAD 100352           // 784*128 = 32*3136
#define NHALF 50176           // 16*3136 = 49*1024
#define RPB 3136              // rows per gemm block
#define HIDST 40              // per-wave hid row stride (80 B)
#define KVST 264              // k_kv LDS row stride

typedef __bf16 bf16x8 __attribute__((ext_vector_type(8)));
typedef __bf16 bf16x4 __attribute__((ext_vector_type(4)));
typedef float f32x4 __attribute__((ext_vector_type(4)));

#define MFMA16(a,b,c) __builtin_amdgcn_mfma_f32_16x16x32_bf16((a),(b),(c),0,0,0)
#define SW(row) (((row)&7)<<3)

// ---------- prep: weights cast/transpose ----------
__global__ void k_prep_w(const float* __restrict__ Wq0, const float* __restrict__ Wk0,
                         const float* __restrict__ Wv0, const float* __restrict__ Wq1,
                         const float* __restrict__ Wk1, const float* __restrict__ Wv1,
                         const float* __restrict__ Wp0, const float* __restrict__ Wp1,
                         __bf16* __restrict__ W0t, __bf16* __restrict__ W1t,
                         __bf16* __restrict__ Wp0t, __bf16* __restrict__ Wp1t) {
  for (int i = blockIdx.x * 256 + threadIdx.x; i < 1343488; i += gridDim.x * 256) {
    if (i < 786432) {                      // W0t [24][256 hid][128 d]
      int g = i >> 15, j = i & 32767;
      int mat = g >> 3, h = g & 7, mcol = j >> 7, k = j & 127;
      const float* src = (mat == 0) ? Wq0 : (mat == 1) ? Wk0 : Wv0;
      W0t[i] = (__bf16)src[h * 32768 + k * 256 + mcol];
    } else if (i < 1179648) {              // W1t [24][64 o][256 hid]
      int t = i - 786432;
      int g = t >> 14, j = t & 16383;
      int mat = g >> 3, h = g & 7, ocol = j >> 8, k = j & 255;
      const float* src = (mat == 0) ? Wq1 : (mat == 1) ? Wk1 : Wv1;
      W1t[t] = (__bf16)src[h * 16384 + k * 64 + ocol];
    } else if (i < 1310720) {              // Wp0t [256][512]
      int t = i - 1179648;
      int col = t >> 9, k = t & 511;
      Wp0t[t] = (__bf16)Wp0[k * 256 + col];
    } else {                               // Wp1t [128][256]
      int t = i - 1310720;
      int col = t >> 8, k = t & 255;
      Wp1t[t] = (__bf16)Wp1[k * 128 + col];
    }
  }
}

// ---------- load 64 X rows (f32 -> bf16 regs), zero beyond NPTS ----------
__device__ __forceinline__ void load_ax(const float* __restrict__ coords,
                                        int base, int l15, int lg, bf16x8 (&ax)[4][4]) {
  #pragma unroll
  for (int jt = 0; jt < 4; ++jt) {
    int row = base + jt * 16 + l15;
    bool ok = row < NPTS;
    #pragma unroll
    for (int ks = 0; ks < 4; ++ks) {
      bf16x8 v = {};
      if (ok) {
        const float4* p4 = (const float4*)(coords + (size_t)row * 128 + ks * 32 + lg * 8);
        float4 f0 = p4[0], f1 = p4[1];
        v[0] = (__bf16)f0.x; v[1] = (__bf16)f0.y; v[2] = (__bf16)f0.z; v[3] = (__bf16)f0.w;
        v[4] = (__bf16)f1.x; v[5] = (__bf16)f1.y; v[6] = (__bf16)f1.z; v[7] = (__bf16)f1.w;
      }
      ax[jt][ks] = v;
    }
  }
}

// ---------- q GEMM: one head per 32-block group, 3136 rows/block ----------
// 256 blocks x 512 thr (8 waves, 64 rows/wave/iter). Weights staged ONCE; row
// loop barrier-free (hid is wave-private). Swapped layer2 -> packed q stores.
__global__ __launch_bounds__(512, 2) void k_qgemm(
    const float* __restrict__ coords, const float* __restrict__ mask,
    const __bf16* __restrict__ W0t, const __bf16* __restrict__ W1t,
    const float* __restrict__ bq0, const float* __restrict__ bq1,
    __bf16* __restrict__ qk_ws)
{
  __shared__ __bf16 sW0[32768];            // 64 KB [256 hid][128 d] swizzled
  __shared__ __bf16 sW1[16384];            // 32 KB [64 o][256 hid] swizzled
  __shared__ __bf16 sHid[8 * 64 * HIDST];  // 40 KB per-wave [64 row][32 col]

  const int tid = threadIdx.x, w = tid >> 6, lane = tid & 63;
  const int l15 = lane & 15, lg = lane >> 4;
  const int h = blockIdx.x >> 5, rb = blockIdx.x & 31;

  const __bf16* w0 = W0t + (size_t)h * 32768;
  const __bf16* w1 = W1t + (size_t)h * 16384;
  #pragma unroll
  for (int i = 0; i < 8; ++i) {
    int u = tid + i * 512, row = u >> 4, k8 = (u & 15) << 3;
    *(bf16x8*)&sW0[(row * 128 + k8) ^ SW(row)] = *(const bf16x8*)(w0 + row * 128 + k8);
  }
  #pragma unroll
  for (int i = 0; i < 4; ++i) {
    int u = tid + i * 512, o = u >> 5, k8 = (u & 31) << 3;
    *(bf16x8*)&sW1[(o * 256 + k8) ^ SW(o)] = *(const bf16x8*)(w1 + o * 256 + k8);
  }
  __syncthreads();

  __bf16* myHid = sHid + w * (64 * HIDST);

  #pragma unroll 1
  for (int it = 0; it < 7; ++it) {
    const int roff = it * 512 + w * 64;
    if (roff >= RPB) break;
    const int base = rb * RPB + roff;

    bf16x8 ax[4][4];
    load_ax(coords, base, l15, lg, ax);

    f32x4 acc2[16];
    #pragma unroll
    for (int i = 0; i < 16; ++i) acc2[i] = f32x4{0.f, 0.f, 0.f, 0.f};

    #pragma unroll 1
    for (int c = 0; c < 8; ++c) {
      f32x4 a1[2][4] = {};
      #pragma unroll
      for (int ks = 0; ks < 4; ++ks) {
        bf16x8 wa[2];
        #pragma unroll
        for (int fi = 0; fi < 2; ++fi) {
          int hl = c * 32 + fi * 16 + l15;
          wa[fi] = *(const bf16x8*)&sW0[(hl * 128 + ks * 32 + lg * 8) ^ SW(hl)];
        }
        #pragma unroll
        for (int fi = 0; fi < 2; ++fi)
          #pragma unroll
          for (int jt = 0; jt < 4; ++jt)
            a1[fi][jt] = MFMA16(wa[fi], ax[jt][ks], a1[fi][jt]);
      }
      #pragma unroll
      for (int fi = 0; fi < 2; ++fi) {
        f32x4 b0v = *(const f32x4*)&bq0[h * 256 + c * 32 + fi * 16 + lg * 4];
        #pragma unroll
        for (int jt = 0; jt < 4; ++jt) {
          bf16x4 hv;
          #pragma unroll
          for (int r = 0; r < 4; ++r) {
            float v = a1[fi][jt][r] + b0v[r];
            hv[r] = (__bf16)(v > 0.f ? v : 0.f);
          }
          *(bf16x4*)&myHid[(jt * 16 + l15) * HIDST + fi * 16 + lg * 4] = hv;
        }
      }
      bf16x8 hb[4], wf[4];
      #pragma unroll
      for (int jt = 0; jt < 4; ++jt)
        hb[jt] = *(const bf16x8*)&myHid[(jt * 16 + l15) * HIDST + lg * 8];
      #pragma unroll
      for (int f = 0; f < 4; ++f) {
        int o = f * 16 + l15;
        wf[f] = *(const bf16x8*)&sW1[(o * 256 + c * 32 + lg * 8) ^ SW(o)];
      }
      #pragma unroll
      for (int ft = 0; ft < 4; ++ft)
        #pragma unroll
        for (int jt = 0; jt < 4; ++jt)
          acc2[ft * 4 + jt] = MFMA16(wf[ft], hb[jt], acc2[ft * 4 + jt]);   // swapped
    }

    float mq[4];
    #pragma unroll
    for (int jt = 0; jt < 4; ++jt) {
      int rq = base + jt * 16 + l15;
      mq[jt] = (rq < NPTS) ? mask[rq] : 0.f;
    }
    #pragma unroll
    for (int ft = 0; ft < 4; ++ft) {
      f32x4 b1v = *(const f32x4*)&bq1[h * 64 + ft * 16 + lg * 4];
      #pragma unroll
      for (int jt = 0; jt < 4; ++jt) {
        bf16x4 qv;
        f32x4 a = acc2[ft * 4 + jt];
        #pragma unroll
        for (int r = 0; r < 4; ++r) {
          float v = (a[r] + b1v[r]) * mq[jt];
          qv[r] = (__bf16)(v > 0.f ? v + 1.f : __expf(v));
        }
        *(bf16x4*)(qk_ws + ((size_t)h * NPAD + base + jt * 16 + l15) * 64 + ft * 16 + lg * 4) = qv;
      }
    }
  }
}

// ---------- k/v GEMM over one half of N (50176 rows) ----------
// 256 blocks (16 mh x 16 chunks) x 512 thr. Writes kkT/vT (half-local rows).
__global__ __launch_bounds__(512, 2) void k_kvgemm(
    const float* __restrict__ coords, const float* __restrict__ mask,
    const __bf16* __restrict__ W0t, const __bf16* __restrict__ W1t,
    const float* __restrict__ bk0, const float* __restrict__ bk1,
    const float* __restrict__ bv0, const float* __restrict__ bv1,
    __bf16* __restrict__ kkTh, __bf16* __restrict__ vTh, int rowOff)
{
  __shared__ __bf16 sW0[32768];
  __shared__ __bf16 sW1[16384];
  __shared__ __bf16 sHid[8 * 64 * HIDST];

  const int tid = threadIdx.x, w = tid >> 6, lane = tid & 63;
  const int l15 = lane & 15, lg = lane >> 4;
  const int mh2 = blockIdx.x >> 4, rb = blockIdx.x & 15;
  const int m2 = mh2 >> 3, h = mh2 & 7;          // m2: 0=k, 1=v

  const __bf16* w0 = W0t + (size_t)((m2 + 1) * 8 + h) * 32768;
  const __bf16* w1 = W1t + (size_t)((m2 + 1) * 8 + h) * 16384;
  #pragma unroll
  for (int i = 0; i < 8; ++i) {
    int u = tid + i * 512, row = u >> 4, k8 = (u & 15) << 3;
    *(bf16x8*)&sW0[(row * 128 + k8) ^ SW(row)] = *(const bf16x8*)(w0 + row * 128 + k8);
  }
  #pragma unroll
  for (int i = 0; i < 4; ++i) {
    int u = tid + i * 512, o = u >> 5, k8 = (u & 31) << 3;
    *(bf16x8*)&sW1[(o * 256 + k8) ^ SW(o)] = *(const bf16x8*)(w1 + o * 256 + k8);
  }
  __syncthreads();

  const float* b0 = m2 ? bv0 : bk0;
  const float* b1 = m2 ? bv1 : bk1;
  __bf16* dstT = m2 ? vTh : kkTh;
  __bf16* myHid = sHid + w * (64 * HIDST);

  #pragma unroll 1
  for (int it = 0; it < 7; ++it) {
    const int roff = it * 512 + w * 64;
    if (roff >= RPB) break;
    const int lbase = rb * RPB + roff;          // half-local
    const int gbase = rowOff + lbase;           // global

    bf16x8 ax[4][4];
    load_ax(coords, gbase, l15, lg, ax);

    f32x4 acc2[16];
    #pragma unroll
    for (int i = 0; i < 16; ++i) acc2[i] = f32x4{0.f, 0.f, 0.f, 0.f};

    #pragma unroll 1
    for (int c = 0; c < 8; ++c) {
      f32x4 a1[2][4] = {};
      #pragma unroll
      for (int ks = 0; ks < 4; ++ks) {
        bf16x8 wa[2];
        #pragma unroll
        for (int fi = 0; fi < 2; ++fi) {
          int hl = c * 32 + fi * 16 + l15;
          wa[fi] = *(const bf16x8*)&sW0[(hl * 128 + ks * 32 + lg * 8) ^ SW(hl)];
        }
        #pragma unroll
        for (int fi = 0; fi < 2; ++fi)
          #pragma unroll
          for (int jt = 0; jt < 4; ++jt)
            a1[fi][jt] = MFMA16(wa[fi], ax[jt][ks], a1[fi][jt]);
      }
      #pragma unroll
      for (int fi = 0; fi < 2; ++fi) {
        f32x4 b0v = *(const f32x4*)&b0[h * 256 + c * 32 + fi * 16 + lg * 4];
        #pragma unroll
        for (int jt = 0; jt < 4; ++jt) {
          bf16x4 hv;
          #pragma unroll
          for (int r = 0; r < 4; ++r) {
            float v = a1[fi][jt][r] + b0v[r];
            hv[r] = (__bf16)(v > 0.f ? v : 0.f);
          }
          *(bf16x4*)&myHid[(jt * 16 + l15) * HIDST + fi * 16 + lg * 4] = hv;
        }
      }
      bf16x8 hb[4], wf[4];
      #pragma unroll
      for (int jt = 0; jt < 4; ++jt)
        hb[jt] = *(const bf16x8*)&myHid[(jt * 16 + l15) * HIDST + lg * 8];
      #pragma unroll
      for (int f = 0; f < 4; ++f) {
        int o = f * 16 + l15;
        wf[f] = *(const bf16x8*)&sW1[(o * 256 + c * 32 + lg * 8) ^ SW(o)];
      }
      #pragma unroll
      for (int jt = 0; jt < 4; ++jt)
        #pragma unroll
        for (int f = 0; f < 4; ++f)
          acc2[jt * 4 + f] = MFMA16(hb[jt], wf[f], acc2[jt * 4 + f]);      // normal
    }

    f32x4 mv[4];
    #pragma unroll
    for (int jt = 0; jt < 4; ++jt) {
      int rv = gbase + jt * 16 + lg * 4;
      #pragma unroll
      for (int r = 0; r < 4; ++r) mv[jt][r] = (rv + r < NPTS) ? mask[rv + r] : 0.f;
    }
    if (m2 == 0) {
      // phi(k), pad rows -> 0, transposed store kkT [h*64+kq][lrow]
      #pragma unroll
      for (int f = 0; f < 4; ++f) {
        float b1s = b1[h * 64 + f * 16 + l15];
        #pragma unroll
        for (int jt = 0; jt < 4; ++jt) {
          bf16x4 k4;
          f32x4 a = acc2[jt * 4 + f];
          #pragma unroll
          for (int r = 0; r < 4; ++r) {
            int row = gbase + jt * 16 + lg * 4 + r;
            float v = (a[r] + b1s) * mv[jt][r];
            k4[r] = (__bf16)((row < NPTS) ? (v > 0.f ? v + 1.f : __expf(v)) : 0.f);
          }
          *(bf16x4*)(dstT + (size_t)(h * 64 + f * 16 + l15) * NHALF + lbase + jt * 16 + lg * 4) = k4;
        }
      }
    } else {
      // v, transposed store vT [h*64+j][lrow]
      #pragma unroll
      for (int f = 0; f < 4; ++f) {
        float b1s = b1[h * 64 + f * 16 + l15];
        #pragma unroll
        for (int jt = 0; jt < 4; ++jt) {
          bf16x4 v4;
          f32x4 a = acc2[jt * 4 + f];
          #pragma unroll
          for (int r = 0; r < 4; ++r)
            v4[r] = (__bf16)((a[r] + b1s) * mv[jt][r]);
          *(bf16x4*)(dstT + (size_t)(h * 64 + f * 16 + l15) * NHALF + lbase + jt * 16 + lg * 4) = v4;
        }
      }
    }
  }
}

// ---------- kv = kkT @ v over one half (split-K 1024 rows), sumk via ones-MFMA ----------
__global__ __launch_bounds__(256) void k_kv(
    const __bf16* __restrict__ kkTh, const __bf16* __restrict__ vTh,
    float* __restrict__ parts_kv, float* __restrict__ parts_sk, int poff)
{
  __shared__ __bf16 sA[64 * KVST];
  __shared__ __bf16 sB[64 * KVST];
  const int tid = threadIdx.x, w = tid >> 6, lane = tid & 63;
  const int l15 = lane & 15, lg = lane >> 4;
  const int sp = blockIdx.x, h = blockIdx.y;
  const int kbase0 = sp * 1024;

  bf16x8 ones;
  #pragma unroll
  for (int e = 0; e < 8; ++e) ones[e] = (__bf16)1.0f;

  f32x4 akv[4] = {};
  f32x4 ask = {};

  #pragma unroll 1
  for (int ch = 0; ch < 4; ++ch) {
    int kb = kbase0 + ch * 256;
    __syncthreads();
    #pragma unroll
    for (int i = 0; i < 8; ++i) {
      int u = tid + i * 256, row = u >> 5, k8 = (u & 31) << 3;
      *(bf16x8*)&sA[row * KVST + k8] = *(const bf16x8*)(kkTh + (size_t)(h * 64 + row) * NHALF + kb + k8);
    }
    #pragma unroll
    for (int i = 0; i < 8; ++i) {
      int u = tid + i * 256, row = u >> 5, k8 = (u & 31) << 3;
      *(bf16x8*)&sB[row * KVST + k8] = *(const bf16x8*)(vTh + (size_t)(h * 64 + row) * NHALF + kb + k8);
    }
    __syncthreads();
    #pragma unroll
    for (int ks = 0; ks < 8; ++ks) {
      bf16x8 a = *(const bf16x8*)&sA[(w * 16 + l15) * KVST + ks * 32 + lg * 8];
      #pragma unroll
      for (int fj = 0; fj < 4; ++fj) {
        bf16x8 b = *(const bf16x8*)&sB[(fj * 16 + l15) * KVST + ks * 32 + lg * 8];
        akv[fj] = MFMA16(a, b, akv[fj]);
      }
      ask = MFMA16(a, ones, ask);
    }
  }
  float* dkv = parts_kv + ((size_t)h * 98 + poff + sp) * 4096;
  #pragma unroll
  for (int fj = 0; fj < 4; ++fj)
    #pragma unroll
    for (int r = 0; r < 4; ++r)
      dkv[(size_t)(w * 16 + lg * 4 + r) * 64 + fj * 16 + l15] = akv[fj][r];
  if (l15 == 0) {
    float* dsk = parts_sk + ((size_t)h * 98 + poff + sp) * 64;
    #pragma unroll
    for (int r = 0; r < 4; ++r) dsk[w * 16 + lg * 4 + r] = ask[r];
  }
}

// ---------- reduce parts -> kvTe bf16 [8][j][kq], sumk f32 [512] ----------
__global__ void k_kvt(const float* __restrict__ parts_kv, const float* __restrict__ parts_sk,
                      __bf16* __restrict__ kvTe, float* __restrict__ sumk) {
  int i = blockIdx.x * 256 + threadIdx.x;
  if (i < 32768) {
    int h = i >> 12, rem = i & 4095;
    float s = 0.f;
    for (int sp = 0; sp < 98; ++sp) s += parts_kv[((size_t)h * 98 + sp) * 4096 + rem];
    int kq = rem >> 6, j = rem & 63;
    kvTe[((size_t)h * 64 + j) * 64 + kq] = (__bf16)s;
  } else if (i < 33280) {
    int t = i - 32768;
    int h = t >> 6, c = t & 63;
    float s = 0.f;
    for (int sp = 0; sp < 98; ++sp) s += parts_sk[((size_t)h * 98 + sp) * 64 + c];
    sumk[t] = s;
  }
}

// ---------- attention normalize + psi MLP (unchanged, verified) ----------
__global__ __launch_bounds__(512, 2) void k_cd(
    const float* __restrict__ mask, const __bf16* __restrict__ qk_ws,
    const __bf16* __restrict__ kvTe, const float* __restrict__ sumk,
    const __bf16* __restrict__ Wp0t, const __bf16* __restrict__ Wp1t,
    const float* __restrict__ bp0, const float* __restrict__ bp1,
    float* __restrict__ out)
{
  __shared__ __bf16 sWp0c[16384];
  __shared__ __bf16 sCat[8192];
  __shared__ __bf16 sH2[32768];
  __shared__ float sSumk[512];

  const int tid = threadIdx.x, w = tid >> 6, lane = tid & 63, l15 = lane & 15, lg = lane >> 4;
  const int rbase = blockIdx.x * 128 + w * 16;
  __bf16* myCat = sCat + w * 1024;
  __bf16* myH2 = sH2 + w * 4096;

  sSumk[tid] = sumk[tid];

  f32x4 acc1[16] = {};
  for (int h = 0; h < 8; ++h) {
    __syncthreads();
    #pragma unroll
    for (int i = 0; i < 4; ++i) {
      int u = tid + i * 512;
      int col = u >> 3, koff = (u & 7) << 3;
      *(bf16x8*)&sWp0c[(col * 64 + koff) ^ SW(col)] =
          *(const bf16x8*)(Wp0t + (size_t)col * 512 + h * 64 + koff);
    }
    __syncthreads();
    bf16x8 axq[2];
    #pragma unroll
    for (int ks = 0; ks < 2; ++ks)
      axq[ks] = *(const bf16x8*)(qk_ws + ((size_t)h * NPAD + rbase + l15) * 64 + ks * 32 + lg * 8);
    f32x4 accn[4] = {};
    #pragma unroll
    for (int ks = 0; ks < 2; ++ks)
      #pragma unroll
      for (int f = 0; f < 4; ++f) {
        bf16x8 bv = *(const bf16x8*)(kvTe + ((size_t)h * 64 + f * 16 + l15) * 64 + ks * 32 + lg * 8);
        accn[f] = MFMA16(axq[ks], bv, accn[f]);
      }
    float p = 0.f;
    #pragma unroll
    for (int ks = 0; ks < 2; ++ks)
      #pragma unroll
      for (int e = 0; e < 8; ++e)
        p += (float)axq[ks][e] * sSumk[h * 64 + ks * 32 + lg * 8 + e];
    p += __shfl_xor(p, 16);
    p += __shfl_xor(p, 32);
    float dinv[4];
    #pragma unroll
    for (int r = 0; r < 4; ++r) {
      float d = __shfl(p, (lane & 48) + ((lane >> 4) << 2) + r);
      d = (d == 0.f) ? 1e-6f : d;
      dinv[r] = 1.f / d;
    }
    #pragma unroll
    for (int f = 0; f < 4; ++f)
      #pragma unroll
      for (int r = 0; r < 4; ++r) {
        int row = lg * 4 + r;
        myCat[(row * 64 + f * 16 + l15) ^ SW(row)] = (__bf16)(accn[f][r] * dinv[r]);
      }
    #pragma unroll
    for (int ks2 = 0; ks2 < 2; ++ks2) {
      bf16x8 aC = *(const bf16x8*)&myCat[(l15 * 64 + ks2 * 32 + lg * 8) ^ SW(l15)];
      #pragma unroll
      for (int f = 0; f < 16; ++f) {
        bf16x8 bw = *(const bf16x8*)&sWp0c[((f * 16 + l15) * 64 + ks2 * 32 + lg * 8) ^ SW(l15)];
        acc1[f] = MFMA16(aC, bw, acc1[f]);
      }
    }
  }
  #pragma unroll
  for (int f = 0; f < 16; ++f) {
    float bias = bp0[f * 16 + l15];
    #pragma unroll
    for (int r = 0; r < 4; ++r) {
      int row = lg * 4 + r;
      float val = acc1[f][r] + bias;
      val = val > 0.f ? val : 0.f;
      myH2[(row * 256 + f * 16 + l15) ^ SW(row)] = (__bf16)val;
    }
  }
  f32x4 acc2[8] = {};
  #pragma unroll
  for (int ks = 0; ks < 8; ++ks) {
    bf16x8 aH = *(const bf16x8*)&myH2[(l15 * 256 + ks * 32 + lg * 8) ^ SW(l15)];
    #pragma unroll
    for (int f = 0; f < 8; ++f) {
      bf16x8 bw = *(const bf16x8*)(Wp1t + (size_t)(f * 16 + l15) * 256 + ks * 32 + lg * 8);
      acc2[f] = MFMA16(aH, bw, acc2[f]);
    }
  }
  float mvr[4];
  #pragma unroll
  for (int r = 0; r < 4; ++r) {
    int grow = rbase + lg * 4 + r;
    mvr[r] = (grow < NPTS) ? mask[grow] : 0.f;
  }
  #pragma unroll
  for (int f = 0; f < 8; ++f) {
    int col = f * 16 + l15;
    float bias = bp1[col];
    #pragma unroll
    for (int r = 0; r < 4; ++r) {
      int grow = rbase + lg * 4 + r;
      if (grow < NPTS) out[(size_t)grow * 128 + col] = (acc2[f][r] + bias) * mvr[r];
    }
  }
}

extern "C" void kernel_launch(void* const* d_in, const int* in_sizes, int n_in,
                              void* d_out, int out_size, void* d_ws, size_t ws_size,
                              hipStream_t stream) {
  const float* coords = (const float*)d_in[0];
  const float* mask   = (const float*)d_in[1];
  const float* Wq0 = (const float*)d_in[2];
  const float* bq0 = (const float*)d_in[3];
  const float* Wq1 = (const float*)d_in[4];
  const float* bq1 = (const float*)d_in[5];
  const float* Wk0 = (const float*)d_in[6];
  const float* bk0 = (const float*)d_in[7];
  const float* Wk1 = (const float*)d_in[8];
  const float* bk1 = (const float*)d_in[9];
  const float* Wv0 = (const float*)d_in[10];
  const float* bv0 = (const float*)d_in[11];
  const float* Wv1 = (const float*)d_in[12];
  const float* bv1 = (const float*)d_in[13];
  const float* Wp0 = (const float*)d_in[14];
  const float* bp0 = (const float*)d_in[15];
  const float* Wp1 = (const float*)d_in[16];
  const float* bp1 = (const float*)d_in[17];
  float* out = (float*)d_out;

  // workspace: region0 (102.8 MB) time-shared between {kkTh|vTh} and qk_ws.
  // Total ~116 MB (proven-safe envelope).
  char* p = (char*)d_ws;
  __bf16* region0  = (__bf16*)p; p += (size_t)8 * NPAD * 64 * 2;    // 102,760,448
  __bf16* qk_ws    = region0;
  __bf16* kkTh     = region0;                                       // 8*64*NHALF
  __bf16* vTh      = region0 + (size_t)8 * 64 * NHALF;              // 8*64*NHALF
  __bf16* W0t      = (__bf16*)p; p += (size_t)24 * 32768 * 2;       //   1,572,864
  __bf16* W1t      = (__bf16*)p; p += (size_t)24 * 16384 * 2;       //     786,432
  __bf16* Wp0t     = (__bf16*)p; p += (size_t)256 * 512 * 2;        //     262,144
  __bf16* Wp1t     = (__bf16*)p; p += (size_t)128 * 256 * 2;        //      65,536
  float*  parts_kv = (float*)p;  p += (size_t)8 * 98 * 4096 * 4;    //  12,845,056
  float*  parts_sk = (float*)p;  p += (size_t)8 * 98 * 64 * 4;      //     200,704
  float*  sumk     = (float*)p;  p += (size_t)512 * 4;              //       2,048
  __bf16* kvTe     = (__bf16*)p; p += (size_t)8 * 64 * 64 * 2;      //      65,536

  k_prep_w<<<1024, 256, 0, stream>>>(Wq0, Wk0, Wv0, Wq1, Wk1, Wv1, Wp0, Wp1,
                                     W0t, W1t, Wp0t, Wp1t);
  // half 0: k/v MLPs -> kkTh/vTh, then consume into kv partials
  k_kvgemm<<<256, 512, 0, stream>>>(coords, mask, W0t, W1t, bk0, bk1, bv0, bv1,
                                    kkTh, vTh, 0);
  k_kv<<<dim3(49, 8), 256, 0, stream>>>(kkTh, vTh, parts_kv, parts_sk, 0);
  // half 1: reuse the same buffers
  k_kvgemm<<<256, 512, 0, stream>>>(coords, mask, W0t, W1t, bk0, bk1, bv0, bv1,
                                    kkTh, vTh, NHALF);
  k_kv<<<dim3(49, 8), 256, 0, stream>>>(kkTh, vTh, parts_kv, parts_sk, 49);
  // q MLP overwrites region0 as qk_ws (kkTh/vTh fully consumed)
  k_qgemm<<<256, 512, 0, stream>>>(coords, mask, W0t, W1t, bq0, bq1, qk_ws);
  k_kvt<<<130, 256, 0, stream>>>(parts_kv, parts_sk, kvTe, sumk);
  k_cd<<<784, 512, 0, stream>>>(mask, qk_ws, kvTe, sumk, Wp0t, Wp1t, bp0, bp1, out);
}